// Round 3
// baseline (1754.089 us; speedup 1.0000x reference)
//
#include <hip/hip_runtime.h>

// DeepRLSNet: batched RLS filter. B=64, N=T=2000, TAPS=64.
// Per step:
//   lam = clip(lambdas[t], 1e-4, 0.9999)
//   Px  = P@x ; den = lam + x.Px ; g = Px/den ; y = w.x
//   w  += g*(d - y)
//   xP  = x@P                 <-- MUST be computed honestly: substituting
//   P   = (P - outer(g, xP))/lam   Px for xP makes asym(P) grow as 1/lam^t
//                                  (verified divergence mode of R1/R2).
//
// Layout: 64 blocks (one per batch) x 256 threads. Thread t = r*4+q owns
// 16-element quarter-rows of BOTH P and PT(=P^T) in registers. PT stays
// bitwise == P^T because both sides of the update use identical products
// (fl(g_c * xP_r), multiplication commutative) and identical scalings.
//
// Divisions by lam and den use a double-float reciprocal (hi+lo correct to
// ~2^-48): 4 VALU ops/element, IEEE-divide quality, no (1+d)^2000 bias.

#define B_ 64
#define N_ 2000
#define TAPS_ 64
#define T_ 2000

__device__ __forceinline__ void recip_df(float v, float& hi, float& lo) {
    double r = 1.0 / (double)v;
    hi = (float)r;
    lo = (float)(r - (double)hi);
}

// ~correctly-rounded x * (hi+lo)  (i.e. x / v where hi+lo ≈ 1/v)
__device__ __forceinline__ float df_mul(float x, float hi, float lo) {
    float p = x * hi;
    float e = fmaf(x, hi, -p);        // exact low part of x*hi
    return p + fmaf(x, lo, e);
}

__global__ __launch_bounds__(256) void rls_kernel(
    const float* __restrict__ x_seq,   // [B, N, TAPS]
    const float* __restrict__ d_seq,   // [B, N]
    const float* __restrict__ lambdas, // [T]
    float* __restrict__ y_out,         // [B, N]
    float* __restrict__ w_out)         // [B, TAPS]
{
    const int b   = blockIdx.x;
    const int tid = threadIdx.x;
    const int r   = tid >> 2;    // row 0..63
    const int q   = tid & 3;     // quarter 0..3
    const int qb  = q << 4;      // column base

    __shared__ __align__(16) float pxs[2][TAPS_];  // Px broadcast
    __shared__ __align__(16) float xps[2][TAPS_];  // xP broadcast

    float P[16], PT[16], w[16];
    #pragma unroll
    for (int j = 0; j < 16; ++j) {
        const float id = (qb + j == r) ? 1.0f : 0.0f;
        P[j] = id; PT[j] = id; w[j] = 0.0f;
    }

    const float* xb = x_seq + (size_t)b * N_ * TAPS_;
    const float* db = d_seq + (size_t)b * N_;
    const int steps = (T_ < N_) ? T_ : N_;

    // preload step-0 inputs (x quarter replicated across row-groups)
    float x[16];
    {
        const float4* xv = (const float4*)(xb + qb);
        #pragma unroll
        for (int j4 = 0; j4 < 4; ++j4) {
            float4 v = xv[j4];
            x[j4*4+0] = v.x; x[j4*4+1] = v.y; x[j4*4+2] = v.z; x[j4*4+3] = v.w;
        }
    }
    float d   = db[0];
    float lam = lambdas[0];

    for (int step = 0; step < steps; ++step) {
        const float lamc = fminf(fmaxf(lam, 1e-4f), 0.9999f);
        float lh, ll;  recip_df(lamc, lh, ll);

        // ---- quarter partials of Px[r] and xP[r] ----
        float pxr = 0.f, xpr = 0.f;
        #pragma unroll
        for (int j = 0; j < 16; ++j) {
            pxr = fmaf(P[j],  x[j], pxr);   // Px_r partial
            xpr = fmaf(PT[j], x[j], xpr);   // xP_r partial (PT row = P col)
        }
        pxr += __shfl_xor(pxr, 1);  xpr += __shfl_xor(xpr, 1);
        pxr += __shfl_xor(pxr, 2);  xpr += __shfl_xor(xpr, 2);

        // ---- publish to LDS (double-buffered; one barrier/step) ----
        float* pb = pxs[step & 1];
        float* qp = xps[step & 1];
        if (q == 0) { pb[r] = pxr; qp[r] = xpr; }
        __syncthreads();

        // ---- prefetch next inputs (after barrier; clamped tail) ----
        const int tn = (step + 1 < steps) ? (step + 1) : (steps - 1);
        float xn[16];
        {
            const float4* xv = (const float4*)(xb + (size_t)tn * TAPS_ + qb);
            #pragma unroll
            for (int j4 = 0; j4 < 4; ++j4) {
                float4 v = xv[j4];
                xn[j4*4+0] = v.x; xn[j4*4+1] = v.y;
                xn[j4*4+2] = v.z; xn[j4*4+3] = v.w;
            }
        }
        const float dn   = db[tn];
        const float lamn = lambdas[tn];

        // ---- read back quarters of Px and xP ----
        float Pxq[16], xPq[16];
        {
            const float4* pv = (const float4*)(pb + qb);
            const float4* qv = (const float4*)(qp + qb);
            #pragma unroll
            for (int j4 = 0; j4 < 4; ++j4) {
                float4 a = pv[j4], c = qv[j4];
                Pxq[j4*4+0] = a.x; Pxq[j4*4+1] = a.y;
                Pxq[j4*4+2] = a.z; Pxq[j4*4+3] = a.w;
                xPq[j4*4+0] = c.x; xPq[j4*4+1] = c.y;
                xPq[j4*4+2] = c.z; xPq[j4*4+3] = c.w;
            }
        }

        // ---- den = lam + x.Px ; y = w.x  (identical in all lanes) ----
        float pd = 0.f, py = 0.f;
        #pragma unroll
        for (int j = 0; j < 16; ++j) {
            pd = fmaf(x[j], Pxq[j], pd);
            py = fmaf(w[j], x[j], py);
        }
        pd += __shfl_xor(pd, 1);  py += __shfl_xor(py, 1);
        pd += __shfl_xor(pd, 2);  py += __shfl_xor(py, 2);

        const float den = lamc + pd;
        const float err = d - py;
        float dh, dl;  recip_df(den, dh, dl);

        if (tid == 0) y_out[(size_t)b * N_ + step] = py;

        // ---- g quarter (bitwise-uniform across all threads) ----
        float gq[16];
        #pragma unroll
        for (int j = 0; j < 16; ++j) gq[j] = df_mul(Pxq[j], dh, dl);
        const float gr = df_mul(pxr, dh, dl);   // == gq value others compute for row r

        // ---- w += g * err ----
        #pragma unroll
        for (int j = 0; j < 16; ++j) w[j] = fmaf(gq[j], err, w[j]);

        // ---- P row update:  P[r][c] = (P[r][c] - g_r * xP_c) / lam ----
        #pragma unroll
        for (int j = 0; j < 16; ++j) {
            const float u = fmaf(-gr, xPq[j], P[j]);
            P[j] = df_mul(u, lh, ll);
        }
        // ---- PT row update: PT[r][c] = P[c][r] = (P[c][r] - g_c * xP_r) / lam ----
        #pragma unroll
        for (int j = 0; j < 16; ++j) {
            const float u = fmaf(-gq[j], xpr, PT[j]);
            PT[j] = df_mul(u, lh, ll);
        }

        // rotate prefetched inputs
        #pragma unroll
        for (int j = 0; j < 16; ++j) x[j] = xn[j];
        d   = dn;
        lam = lamn;
    }

    // ---- final weights: row-group 0 holds a full replica across q ----
    if (r == 0) {
        float4* wo = (float4*)(w_out + (size_t)b * TAPS_ + qb);
        #pragma unroll
        for (int j4 = 0; j4 < 4; ++j4) {
            wo[j4] = make_float4(w[j4*4+0], w[j4*4+1], w[j4*4+2], w[j4*4+3]);
        }
    }
}

extern "C" void kernel_launch(void* const* d_in, const int* in_sizes, int n_in,
                              void* d_out, int out_size, void* d_ws, size_t ws_size,
                              hipStream_t stream) {
    const float* x_seq   = (const float*)d_in[0];
    const float* d_seq   = (const float*)d_in[1];
    const float* lambdas = (const float*)d_in[2];

    float* y_out = (float*)d_out;                      // B*N floats
    float* w_out = (float*)d_out + (size_t)B_ * N_;    // B*TAPS floats

    rls_kernel<<<B_, 256, 0, stream>>>(x_seq, d_seq, lambdas, y_out, w_out);
}

// Round 4
// 1385.810 us; speedup vs baseline: 1.2657x; 1.2657x over previous
//
#include <hip/hip_runtime.h>

// DeepRLSNet: batched RLS filter. B=64, N=T=2000, TAPS=64.
// Per step:
//   lam = clip(lambdas[t], 1e-4, 0.9999)
//   Px  = P@x ; den = lam + x.Px ; g = Px/den ; y = w.x
//   w  += g*(d - y)
//   xP  = x@P            (honest xP: substituting Px for xP makes asym(P)
//   P   = (P - outer(g, xP))/lam    grow as 1/lam^t — R1/R2 divergence mode)
//
// Layout: 64 blocks (one per batch) x 256 threads. Thread t = r*4+q owns
// 16-element quarter-rows of BOTH P and PT(=P^T). PT stays bitwise == P^T:
// both sides compute the same fused fmaf(-g_j, xP_r, prev) on identical bits
// (g_j/xP_r are bitwise-uniform via LDS broadcast + commutative butterflies),
// then the same *inv_lam multiply.
//
// R4 vs R3: all-fp32 arithmetic (IEEE 1.0f/x divides; no double-float), w.x
// butterfly hoisted before the barrier, 2x unroll with x-buffer role swap.

#define B_ 64
#define N_ 2000
#define TAPS_ 64
#define T_ 2000

__global__ __launch_bounds__(256) void rls_kernel(
    const float* __restrict__ x_seq,   // [B, N, TAPS]
    const float* __restrict__ d_seq,   // [B, N]
    const float* __restrict__ lambdas, // [T]
    float* __restrict__ y_out,         // [B, N]
    float* __restrict__ w_out)         // [B, TAPS]
{
    const int b   = blockIdx.x;
    const int tid = threadIdx.x;
    const int r   = tid >> 2;    // row 0..63
    const int q   = tid & 3;     // quarter 0..3
    const int qb  = q << 4;      // column base

    __shared__ __align__(16) float pxs[2][TAPS_];  // Px broadcast
    __shared__ __align__(16) float xps[2][TAPS_];  // xP broadcast

    float P[16], PT[16], w[16];
    #pragma unroll
    for (int j = 0; j < 16; ++j) {
        const float id = (qb + j == r) ? 1.0f : 0.0f;
        P[j] = id; PT[j] = id; w[j] = 0.0f;
    }

    const float* xb = x_seq + (size_t)b * N_ * TAPS_;
    const float* db = d_seq + (size_t)b * N_;
    const int steps = (T_ < N_) ? T_ : N_;   // 2000 (even)

    float xA[16], xB[16];
    {
        const float4* xv = (const float4*)(xb + qb);
        #pragma unroll
        for (int j4 = 0; j4 < 4; ++j4) {
            float4 v = xv[j4];
            xA[j4*4+0] = v.x; xA[j4*4+1] = v.y;
            xA[j4*4+2] = v.z; xA[j4*4+3] = v.w;
        }
    }
    float d   = db[0];
    float lam = lambdas[0];

    auto step_body = [&](int step, float (&x)[16], float (&xn)[16], int buf) {
        const float lamc    = fminf(fmaxf(lam, 1e-4f), 0.9999f);
        const float inv_lam = 1.0f / lamc;      // IEEE; uniform in all lanes

        // ---- quarter partials of Px[r], xP[r], and w.x (pre-barrier) ----
        float pxr = 0.f, xpr = 0.f, py = 0.f;
        #pragma unroll
        for (int j = 0; j < 16; ++j) {
            pxr = fmaf(P[j],  x[j], pxr);
            xpr = fmaf(PT[j], x[j], xpr);
            py  = fmaf(w[j],  x[j], py);
        }
        pxr += __shfl_xor(pxr, 1);  xpr += __shfl_xor(xpr, 1);  py += __shfl_xor(py, 1);
        pxr += __shfl_xor(pxr, 2);  xpr += __shfl_xor(xpr, 2);  py += __shfl_xor(py, 2);

        // ---- publish Px / xP (double-buffered; one barrier per step) ----
        float* pb = pxs[buf];
        float* qp = xps[buf];
        if (q == 0) { pb[r] = pxr; qp[r] = xpr; }
        __syncthreads();

        // ---- prefetch next step's inputs (after barrier; clamped tail) ----
        const int tn = (step + 1 < steps) ? (step + 1) : (steps - 1);
        {
            const float4* xv = (const float4*)(xb + (size_t)tn * TAPS_ + qb);
            #pragma unroll
            for (int j4 = 0; j4 < 4; ++j4) {
                float4 v = xv[j4];
                xn[j4*4+0] = v.x; xn[j4*4+1] = v.y;
                xn[j4*4+2] = v.z; xn[j4*4+3] = v.w;
            }
        }
        const float dn   = db[tn];
        const float lamn = lambdas[tn];

        // ---- read back quarters of Px and xP ----
        float Pxq[16], xPq[16];
        {
            const float4* pv = (const float4*)(pb + qb);
            const float4* qv = (const float4*)(qp + qb);
            #pragma unroll
            for (int j4 = 0; j4 < 4; ++j4) {
                float4 a = pv[j4], c = qv[j4];
                Pxq[j4*4+0] = a.x; Pxq[j4*4+1] = a.y;
                Pxq[j4*4+2] = a.z; Pxq[j4*4+3] = a.w;
                xPq[j4*4+0] = c.x; xPq[j4*4+1] = c.y;
                xPq[j4*4+2] = c.z; xPq[j4*4+3] = c.w;
            }
        }

        // ---- den = lam + x.Px (only remaining post-barrier reduce) ----
        float pd = 0.f;
        #pragma unroll
        for (int j = 0; j < 16; ++j) pd = fmaf(x[j], Pxq[j], pd);
        pd += __shfl_xor(pd, 1);
        pd += __shfl_xor(pd, 2);

        const float den     = lamc + pd;
        const float inv_den = 1.0f / den;       // IEEE; uniform in all lanes
        const float err     = d - py;

        if (tid == 0) y_out[(size_t)b * N_ + step] = py;

        // ---- g (bitwise-uniform across owners/readers) ----
        float gq[16];
        #pragma unroll
        for (int j = 0; j < 16; ++j) gq[j] = Pxq[j] * inv_den;
        const float gr = pxr * inv_den;  // row r's g; == gq[.] bits elsewhere

        // ---- w += g * err ----
        #pragma unroll
        for (int j = 0; j < 16; ++j) w[j] = fmaf(gq[j], err, w[j]);

        // ---- P[r][c]  = (P[r][c]  - g_r * xP_c) * inv_lam ----
        #pragma unroll
        for (int j = 0; j < 16; ++j)
            P[j] = fmaf(-gr, xPq[j], P[j]) * inv_lam;
        // ---- PT[r][c] = P[c][r] = (P[c][r] - g_c * xP_r) * inv_lam ----
        #pragma unroll
        for (int j = 0; j < 16; ++j)
            PT[j] = fmaf(-gq[j], xpr, PT[j]) * inv_lam;

        d   = dn;
        lam = lamn;
    };

    for (int step = 0; step < steps; step += 2) {
        step_body(step,     xA, xB, 0);
        step_body(step + 1, xB, xA, 1);
    }

    // ---- final weights: row-group 0 holds a full replica across q ----
    if (r == 0) {
        float4* wo = (float4*)(w_out + (size_t)b * TAPS_ + qb);
        #pragma unroll
        for (int j4 = 0; j4 < 4; ++j4) {
            wo[j4] = make_float4(w[j4*4+0], w[j4*4+1], w[j4*4+2], w[j4*4+3]);
        }
    }
}

extern "C" void kernel_launch(void* const* d_in, const int* in_sizes, int n_in,
                              void* d_out, int out_size, void* d_ws, size_t ws_size,
                              hipStream_t stream) {
    const float* x_seq   = (const float*)d_in[0];
    const float* d_seq   = (const float*)d_in[1];
    const float* lambdas = (const float*)d_in[2];

    float* y_out = (float*)d_out;                      // B*N floats
    float* w_out = (float*)d_out + (size_t)B_ * N_;    // B*TAPS floats

    rls_kernel<<<B_, 256, 0, stream>>>(x_seq, d_seq, lambdas, y_out, w_out);
}

// Round 5
// 1300.591 us; speedup vs baseline: 1.3487x; 1.0655x over previous
//
#include <hip/hip_runtime.h>

// DeepRLSNet: batched RLS filter. B=64, N=T=2000, TAPS=64.
// Per step:
//   lam = clip(lambdas[t], 1e-4, 0.9999)
//   Px  = P@x ; den = lam + x.Px ; g = Px/den ; y = w.x
//   w  += g*(d - y)
//   xP  = x@P            (honest xP: substituting Px for xP makes asym(P)
//   P   = (P - outer(g, xP))/lam    grow as 1/lam^t — R1/R2 divergence mode)
//
// Layout: 64 blocks (one per batch) x 256 threads. Thread t = r*4+q owns
// 16-element quarter-rows of BOTH P and PT(=P^T). PT stays bitwise == P^T
// (both sides use identical fused products on identical broadcast bits).
//
// R5 vs R4 (latency-bound regime, 1 wave/SIMD):
//  - raw `s_waitcnt lgkmcnt(0); s_barrier` instead of __syncthreads():
//    does NOT drain vmcnt, so global x-prefetch loads stay in flight
//    across the per-step barrier.
//  - distance-2 x prefetch (4 register buffers, 4-body unroll) to cover
//    ~900-cyc HBM latency with two step periods.
//  - d_seq/lambdas staged into LDS once; per-step scalar reads are
//    uniform-address ds_reads consumed only post-barrier.
//  - 4-accumulator den reduction (shorter post-barrier dependent chain).

#define B_ 64
#define N_ 2000
#define TAPS_ 64
#define T_ 2000
#define STEPS_ 2000   // min(T_, N_), divisible by 4

__device__ __forceinline__ void lds_barrier() {
    // LDS-only fence + barrier: leaves global (vmcnt) traffic in flight.
    asm volatile("s_waitcnt lgkmcnt(0)\n\ts_barrier" ::: "memory");
}

__global__ __launch_bounds__(256, 1) void rls_kernel(
    const float* __restrict__ x_seq,   // [B, N, TAPS]
    const float* __restrict__ d_seq,   // [B, N]
    const float* __restrict__ lambdas, // [T]
    float* __restrict__ y_out,         // [B, N]
    float* __restrict__ w_out)         // [B, TAPS]
{
    const int b   = blockIdx.x;
    const int tid = threadIdx.x;
    const int r   = tid >> 2;    // row 0..63
    const int q   = tid & 3;     // quarter 0..3
    const int qb  = q << 4;      // column base

    __shared__ __align__(16) float pxs[2][TAPS_];  // Px broadcast (dbuf)
    __shared__ __align__(16) float xps[2][TAPS_];  // xP broadcast (dbuf)
    __shared__ __align__(16) float d_lds[STEPS_];
    __shared__ __align__(16) float lam_lds[STEPS_];

    const float* xb = x_seq + (size_t)b * N_ * TAPS_;
    const float* db = d_seq + (size_t)b * N_;

    // ---- one-time stage of d and lambda into LDS ----
    for (int idx = tid; idx < STEPS_; idx += 256) {
        d_lds[idx]   = db[idx];
        lam_lds[idx] = lambdas[idx];
    }

    float P[16], PT[16], w[16];
    #pragma unroll
    for (int j = 0; j < 16; ++j) {
        const float id = (qb + j == r) ? 1.0f : 0.0f;
        P[j] = id; PT[j] = id; w[j] = 0.0f;
    }

    auto loadx = [&](float (&dst)[16], int t) {
        const float4* xv = (const float4*)(xb + (size_t)t * TAPS_ + qb);
        #pragma unroll
        for (int j4 = 0; j4 < 4; ++j4) {
            float4 v = xv[j4];
            dst[j4*4+0] = v.x; dst[j4*4+1] = v.y;
            dst[j4*4+2] = v.z; dst[j4*4+3] = v.w;
        }
    };

    float xA[16], xB[16], xC[16], xD[16];
    loadx(xA, 0);
    loadx(xB, 1);

    lds_barrier();   // d_lds/lam_lds visible to all waves

    auto body = [&](int step, float (&x)[16], float (&xn)[16]) {
        // step's d/lam from LDS: uniform-address ds_read, needed only
        // post-barrier (~300 cyc of slack).
        const float d_t   = d_lds[step];
        const float lam_t = lam_lds[step];

        // ---- pre-barrier: quarter partials of Px[r], xP[r], w.x ----
        float pxr = 0.f, xpr = 0.f, py = 0.f;
        #pragma unroll
        for (int j = 0; j < 16; ++j) {
            pxr = fmaf(P[j],  x[j], pxr);
            xpr = fmaf(PT[j], x[j], xpr);
            py  = fmaf(w[j],  x[j], py);
        }
        pxr += __shfl_xor(pxr, 1);  xpr += __shfl_xor(xpr, 1);  py += __shfl_xor(py, 1);
        pxr += __shfl_xor(pxr, 2);  xpr += __shfl_xor(xpr, 2);  py += __shfl_xor(py, 2);

        float* pb = pxs[step & 1];
        float* qp = xps[step & 1];
        if (q == 0) { pb[r] = pxr; qp[r] = xpr; }
        lds_barrier();

        // ---- distance-2 x prefetch (rides across raw barriers) ----
        const int tn = (step + 2 < STEPS_) ? (step + 2) : (STEPS_ - 1);
        loadx(xn, tn);

        // ---- read back quarters of Px and xP ----
        float Pxq[16], xPq[16];
        {
            const float4* pv = (const float4*)(pb + qb);
            const float4* qv = (const float4*)(qp + qb);
            #pragma unroll
            for (int j4 = 0; j4 < 4; ++j4) {
                float4 a = pv[j4], c = qv[j4];
                Pxq[j4*4+0] = a.x; Pxq[j4*4+1] = a.y;
                Pxq[j4*4+2] = a.z; Pxq[j4*4+3] = a.w;
                xPq[j4*4+0] = c.x; xPq[j4*4+1] = c.y;
                xPq[j4*4+2] = c.z; xPq[j4*4+3] = c.w;
            }
        }

        // ---- den = lam + x.Px  (4-accumulator tree, short chain) ----
        float p0 = 0.f, p1 = 0.f, p2 = 0.f, p3 = 0.f;
        #pragma unroll
        for (int j = 0; j < 16; j += 4) {
            p0 = fmaf(x[j+0], Pxq[j+0], p0);
            p1 = fmaf(x[j+1], Pxq[j+1], p1);
            p2 = fmaf(x[j+2], Pxq[j+2], p2);
            p3 = fmaf(x[j+3], Pxq[j+3], p3);
        }
        float pd = (p0 + p1) + (p2 + p3);
        pd += __shfl_xor(pd, 1);
        pd += __shfl_xor(pd, 2);

        const float lamc    = fminf(fmaxf(lam_t, 1e-4f), 0.9999f);
        const float inv_lam = 1.0f / lamc;      // IEEE; uniform
        const float den     = lamc + pd;
        const float inv_den = 1.0f / den;       // IEEE; uniform
        const float err     = d_t - py;

        if (tid == 0) y_out[(size_t)b * N_ + step] = py;

        // ---- g (bitwise-uniform across owners/readers) ----
        float gq[16];
        #pragma unroll
        for (int j = 0; j < 16; ++j) gq[j] = Pxq[j] * inv_den;
        const float gr = pxr * inv_den;

        // ---- w += g * err ----
        #pragma unroll
        for (int j = 0; j < 16; ++j) w[j] = fmaf(gq[j], err, w[j]);

        // ---- P[r][c]  = (P[r][c]  - g_r * xP_c) * inv_lam ----
        #pragma unroll
        for (int j = 0; j < 16; ++j)
            P[j] = fmaf(-gr, xPq[j], P[j]) * inv_lam;
        // ---- PT[r][c] = P[c][r] = (P[c][r] - g_c * xP_r) * inv_lam ----
        #pragma unroll
        for (int j = 0; j < 16; ++j)
            PT[j] = fmaf(-gq[j], xpr, PT[j]) * inv_lam;
    };

    for (int t = 0; t < STEPS_; t += 4) {
        body(t + 0, xA, xC);
        body(t + 1, xB, xD);
        body(t + 2, xC, xA);
        body(t + 3, xD, xB);
    }

    // ---- final weights: row-group 0 holds a full replica across q ----
    if (r == 0) {
        float4* wo = (float4*)(w_out + (size_t)b * TAPS_ + qb);
        #pragma unroll
        for (int j4 = 0; j4 < 4; ++j4) {
            wo[j4] = make_float4(w[j4*4+0], w[j4*4+1], w[j4*4+2], w[j4*4+3]);
        }
    }
}

extern "C" void kernel_launch(void* const* d_in, const int* in_sizes, int n_in,
                              void* d_out, int out_size, void* d_ws, size_t ws_size,
                              hipStream_t stream) {
    const float* x_seq   = (const float*)d_in[0];
    const float* d_seq   = (const float*)d_in[1];
    const float* lambdas = (const float*)d_in[2];

    float* y_out = (float*)d_out;                      // B*N floats
    float* w_out = (float*)d_out + (size_t)B_ * N_;    // B*TAPS floats

    rls_kernel<<<B_, 256, 0, stream>>>(x_seq, d_seq, lambdas, y_out, w_out);
}